// Round 13
// baseline (124.440 us; speedup 1.0000x reference)
//
#include <hip/hip_runtime.h>
#include <math.h>

typedef _Float16 f16x8 __attribute__((ext_vector_type(8)));
typedef __fp16   fp16v2 __attribute__((ext_vector_type(2)));
typedef float    f32x16 __attribute__((ext_vector_type(16)));

#define THREADS 256
#define YCHUNK  4096  // y points per LDS chunk (32 KB)
#define XPB     128   // x points per block (4 waves * 32 cols)

static __device__ inline unsigned pk2(float a, float b) {
    fp16v2 h = __builtin_amdgcn_cvt_pkrtz(a, b);
    return __builtin_bit_cast(unsigned, h);
}

static __device__ inline void packwrite(uint2* dst, float4 f0, float4 f1,
                                        float4 f2) {
    float n0 = fmaf(f0.x, f0.x, fmaf(f0.y, f0.y, f0.z * f0.z));
    float n1 = fmaf(f0.w, f0.w, fmaf(f1.x, f1.x, f1.y * f1.y));
    float n2 = fmaf(f1.z, f1.z, fmaf(f1.w, f1.w, f2.x * f2.x));
    float n3 = fmaf(f2.y, f2.y, fmaf(f2.z, f2.z, f2.w * f2.w));
    dst[0] = make_uint2(pk2(f0.x, f0.y), pk2(f0.z, n0));
    dst[1] = make_uint2(pk2(f0.w, f1.x), pk2(f1.y, n1));
    dst[2] = make_uint2(pk2(f1.z, f1.w), pk2(f2.x, n2));
    dst[3] = make_uint2(pk2(f2.y, f2.z), pk2(f2.w, n3));
}

// MEASUREMENT ROUND. min is idempotent -> repeating compute REP x leaves the
// output bit-identical but makes the dispatch long enough to crack rocprof's
// top-5 (harness fills occlude anything < 39us). REP is a runtime arg so the
// compiler can't unroll/CSE the repeats away.
// V0 = current inner loop (loads immediately before their MFMAs).
// V1 = depth-1 cyclic software pipeline (group g+1 ds_reads issued before
//      folding group g; wrap &127 keeps it branchless; refolds are no-ops).

#define PREAMBLE                                                            \
    const int dir = blockIdx.z;                                             \
    const float* xsrc = dir == 0 ? pred : targ;                             \
    const float* ysrc = dir == 0 ? targ : pred;                             \
    const int b = blockIdx.y;                                               \
    __shared__ uint2 sy[YCHUNK];                                            \
    __shared__ float swave[4];                                              \
    const int tid  = threadIdx.x;                                           \
    const int lane = tid & 63;                                              \
    const int wave = tid >> 6;                                              \
    const int col  = lane & 31;                                             \
    const size_t xi = (size_t)(b * N + blockIdx.x * XPB + wave * 32 + col) * 3; \
    const float x0 = xsrc[xi], x1 = xsrc[xi + 1], x2 = xsrc[xi + 2];        \
    const bool act = lane < 32;                                             \
    f16x8 bf;                                                               \
    bf[0] = act ? (_Float16)(-2.0f * x0) : (_Float16)0.0f;                  \
    bf[1] = act ? (_Float16)(-2.0f * x1) : (_Float16)0.0f;                  \
    bf[2] = act ? (_Float16)(-2.0f * x2) : (_Float16)0.0f;                  \
    bf[3] = act ? (_Float16)1.0f : (_Float16)0.0f;                          \
    bf[4] = bf[5] = bf[6] = bf[7] = (_Float16)0.0f;                         \
    f32x16 zacc;                                                            \
    f32x16 vmin;                                                            \
    _Pragma("unroll")                                                       \
    for (int r = 0; r < 16; ++r) { zacc[r] = 0.0f; vmin[r] = INFINITY; }

#define STAGE(c)                                                            \
    {                                                                       \
        const float4* yf4 = (const float4*)(ysrc + (size_t)b * N * 3        \
                                            + (size_t)(c) * YCHUNK * 3);    \
        _Pragma("unroll")                                                   \
        for (int k = 0; k < 4; ++k) {                                       \
            const int fb = k * THREADS * 3 + tid * 3;                       \
            packwrite(&sy[(k * THREADS + tid) * 4], yf4[fb], yf4[fb + 1],   \
                      yf4[fb + 2]);                                         \
        }                                                                   \
    }

#define EPILOGUE                                                            \
    float v = vmin[0];                                                      \
    _Pragma("unroll")                                                       \
    for (int r = 1; r < 16; ++r) v = fminf(v, vmin[r]);                     \
    v = fminf(v, __shfl_xor(v, 32));                                        \
    float d = v + fmaf(x0, x0, fmaf(x1, x1, x2 * x2));                      \
    _Pragma("unroll")                                                       \
    for (int off = 16; off > 0; off >>= 1) d += __shfl_xor(d, off);         \
    if (lane == 0) swave[wave] = d;                                         \
    __syncthreads();                                                        \
    if (tid == 0) {                                                         \
        float s = swave[0] + swave[1] + swave[2] + swave[3];                \
        int bid = blockIdx.x + gridDim.x * (blockIdx.y + gridDim.y * blockIdx.z); \
        partials[bid] = s;                                                  \
    }

#define MF(X)                                                               \
    __builtin_amdgcn_mfma_f32_32x32x16_f16(                                 \
        __builtin_bit_cast(f16x8, make_uint4((X).x, (X).y, 0u, 0u)),        \
        bf, zacc, 0, 0, 0)

// ---------------- V0: loads immediately before MFMAs ----------------
__global__ __launch_bounds__(THREADS, 2) void chamfer_v0(
    const float* __restrict__ pred, const float* __restrict__ targ,
    float* __restrict__ partials, int N, int REP)
{
    PREAMBLE
    for (int c = 0; c < N / YCHUNK; ++c) {
        __syncthreads();
        STAGE(c)
        __syncthreads();
        for (int rep = 0; rep < REP; ++rep) {
            for (int i = 0; i < YCHUNK / 32; i += 8) {
                uint2 lo0 = sy[(i + 0) * 32 + col];
                uint2 lo1 = sy[(i + 1) * 32 + col];
                uint2 lo2 = sy[(i + 2) * 32 + col];
                uint2 lo3 = sy[(i + 3) * 32 + col];
                uint2 lo4 = sy[(i + 4) * 32 + col];
                uint2 lo5 = sy[(i + 5) * 32 + col];
                uint2 lo6 = sy[(i + 6) * 32 + col];
                uint2 lo7 = sy[(i + 7) * 32 + col];
                f32x16 ac0 = MF(lo0); f32x16 ac1 = MF(lo1);
                f32x16 ac2 = MF(lo2); f32x16 ac3 = MF(lo3);
                f32x16 ac4 = MF(lo4); f32x16 ac5 = MF(lo5);
                f32x16 ac6 = MF(lo6); f32x16 ac7 = MF(lo7);
#pragma unroll
                for (int r = 0; r < 16; ++r) {
                    vmin[r] = fminf(fminf(vmin[r], ac0[r]), ac1[r]);
                    vmin[r] = fminf(fminf(vmin[r], ac2[r]), ac3[r]);
                    vmin[r] = fminf(fminf(vmin[r], ac4[r]), ac5[r]);
                    vmin[r] = fminf(fminf(vmin[r], ac6[r]), ac7[r]);
                }
            }
        }
    }
    EPILOGUE
}

// ---------------- V1: depth-1 cyclic software pipeline ----------------
#define LD8(P, g)                                                           \
    P##0 = sy[((((g) * 8 + 0) & 127) * 32) + col];                          \
    P##1 = sy[((((g) * 8 + 1) & 127) * 32) + col];                          \
    P##2 = sy[((((g) * 8 + 2) & 127) * 32) + col];                          \
    P##3 = sy[((((g) * 8 + 3) & 127) * 32) + col];                          \
    P##4 = sy[((((g) * 8 + 4) & 127) * 32) + col];                          \
    P##5 = sy[((((g) * 8 + 5) & 127) * 32) + col];                          \
    P##6 = sy[((((g) * 8 + 6) & 127) * 32) + col];                          \
    P##7 = sy[((((g) * 8 + 7) & 127) * 32) + col]

#define MF_FOLD(P)                                                          \
    {                                                                       \
        f32x16 A0 = MF(P##0); f32x16 A1 = MF(P##1);                         \
        f32x16 A2 = MF(P##2); f32x16 A3 = MF(P##3);                         \
        f32x16 A4 = MF(P##4); f32x16 A5 = MF(P##5);                         \
        f32x16 A6 = MF(P##6); f32x16 A7 = MF(P##7);                         \
        _Pragma("unroll")                                                   \
        for (int r = 0; r < 16; ++r) {                                      \
            vmin[r] = fminf(fminf(vmin[r], A0[r]), A1[r]);                  \
            vmin[r] = fminf(fminf(vmin[r], A2[r]), A3[r]);                  \
            vmin[r] = fminf(fminf(vmin[r], A4[r]), A5[r]);                  \
            vmin[r] = fminf(fminf(vmin[r], A6[r]), A7[r]);                  \
        }                                                                   \
    }

__global__ __launch_bounds__(THREADS, 2) void chamfer_v1(
    const float* __restrict__ pred, const float* __restrict__ targ,
    float* __restrict__ partials, int N, int REP)
{
    PREAMBLE
    uint2 pa0, pa1, pa2, pa3, pa4, pa5, pa6, pa7;
    uint2 pb0, pb1, pb2, pb3, pb4, pb5, pb6, pb7;
    for (int c = 0; c < N / YCHUNK; ++c) {
        __syncthreads();
        STAGE(c)
        __syncthreads();
        for (int rep = 0; rep < REP; ++rep) {
            LD8(pa, 0);
            for (int g = 0; g < 16; g += 2) {
                LD8(pb, g + 1);   // prefetch: latency hides under MF_FOLD(pa)
                MF_FOLD(pa);      // fold group g (already resident)
                LD8(pa, g + 2);   // prefetch g+2 (wraps to 0 at end: no-op refold)
                MF_FOLD(pb);      // fold group g+1
            }
        }
    }
    EPILOGUE
}

__global__ __launch_bounds__(512) void finalize(
    const float* __restrict__ partials, const float* __restrict__ fbpp,
    float* __restrict__ out, int nPartials, int totalPts)
{
    __shared__ float sw[8];
    const int tid = threadIdx.x;
    float v = (tid < nPartials) ? partials[tid] : 0.0f;
#pragma unroll
    for (int off = 32; off > 0; off >>= 1) v += __shfl_xor(v, off);
    if ((tid & 63) == 0) sw[tid >> 6] = v;
    __syncthreads();
    if (tid == 0) {
        float t = 0.0f;
#pragma unroll
        for (int w = 0; w < 8; ++w) t += sw[w];
        float dist = t / (float)totalPts;
        float rate = fbpp[0];
        out[0] = dist + rate;
        out[1] = dist;
        out[2] = rate;
    }
}

extern "C" void kernel_launch(void* const* d_in, const int* in_sizes, int n_in,
                              void* d_out, int out_size, void* d_ws, size_t ws_size,
                              hipStream_t stream) {
    const float* pred = (const float*)d_in[0];
    const float* targ = (const float*)d_in[1];
    const float* fbpp = (const float*)d_in[2];
    float* out = (float*)d_out;

    const int B = 4;
    const int N = in_sizes[0] / (B * 3);   // 8192
    float* partials  = (float*)d_ws;       // 512 floats (real, from V0)
    float* partials2 = partials + 512;     // 512 floats (V1 probe)

    dim3 grid(N / XPB, B, 2);              // (64, 4, 2) = 512 blocks
    const int REP = 4;                     // runtime arg: no unroll/CSE

    chamfer_v0<<<grid, THREADS, 0, stream>>>(pred, targ, partials, N, REP);
    chamfer_v1<<<grid, THREADS, 0, stream>>>(pred, targ, partials2, N, REP);

    const int nPartials = (N / XPB) * B * 2;  // 512
    finalize<<<1, 512, 0, stream>>>(partials, fbpp, out, nPartials, B * N);
}

// Round 14
// 24.926 us; speedup vs baseline: 4.9925x; 4.9925x over previous
//
#include <hip/hip_runtime.h>
#include <math.h>

typedef _Float16 f16x8 __attribute__((ext_vector_type(8)));
typedef __fp16   fp16v2 __attribute__((ext_vector_type(2)));
typedef float    f32x16 __attribute__((ext_vector_type(16)));

#define THREADS 256
#define YCHUNK  4096  // y points per LDS chunk (32 KB)
#define XPB     128   // x points per block (4 waves * 32 cols)

static __device__ inline unsigned pk2(float a, float b) {
    fp16v2 h = __builtin_amdgcn_cvt_pkrtz(a, b);
    return __builtin_bit_cast(unsigned, h);
}

static __device__ inline void packwrite(uint2* dst, float4 f0, float4 f1,
                                        float4 f2) {
    float n0 = fmaf(f0.x, f0.x, fmaf(f0.y, f0.y, f0.z * f0.z));
    float n1 = fmaf(f0.w, f0.w, fmaf(f1.x, f1.x, f1.y * f1.y));
    float n2 = fmaf(f1.z, f1.z, fmaf(f1.w, f1.w, f2.x * f2.x));
    float n3 = fmaf(f2.y, f2.y, fmaf(f2.z, f2.z, f2.w * f2.w));
    dst[0] = make_uint2(pk2(f0.x, f0.y), pk2(f0.z, n0));
    dst[1] = make_uint2(pk2(f0.w, f1.x), pk2(f1.y, n1));
    dst[2] = make_uint2(pk2(f1.z, f1.w), pk2(f2.x, n2));
    dst[3] = make_uint2(pk2(f2.y, f2.z), pk2(f2.w, n3));
}

// R12 diagnosis: compiler put the 8 f32x16 MFMA accumulators in AGPRs
// (VGPR_Count=52) -> every fold paid a v_accvgpr_read per element (3x VALU
// bloat). Fix: (a) fold MFMA PAIRS immediately so only 2 pairs are live
// (<=64 acc regs), (b) inline-asm v_min3_f32 with "v" constraints forces
// VGPR residency and guarantees min3 fusion (8 min3/MFMA = the floor),
// (c) depth-2 pair pipeline hides MFMA latency.
__global__ __launch_bounds__(THREADS, 2) void chamfer_kernel(
    const float* __restrict__ pred, const float* __restrict__ targ,
    float* __restrict__ partials, int N)
{
    const int dir = blockIdx.z;
    const float* xsrc = dir == 0 ? pred : targ;
    const float* ysrc = dir == 0 ? targ : pred;
    const int b = blockIdx.y;

    __shared__ uint2 sy[YCHUNK];
    __shared__ float swave[4];

    const int tid  = threadIdx.x;
    const int lane = tid & 63;
    const int wave = tid >> 6;
    const int col  = lane & 31;

    // This lane's x column (lanes 32-63 duplicate lanes 0-31).
    const size_t xi = (size_t)(b * N + blockIdx.x * XPB + wave * 32 + col) * 3;
    const float x0 = xsrc[xi], x1 = xsrc[xi + 1], x2 = xsrc[xi + 2];

    const bool act = lane < 32;
    f16x8 bf;
    bf[0] = act ? (_Float16)(-2.0f * x0) : (_Float16)0.0f;
    bf[1] = act ? (_Float16)(-2.0f * x1) : (_Float16)0.0f;
    bf[2] = act ? (_Float16)(-2.0f * x2) : (_Float16)0.0f;
    bf[3] = act ? (_Float16)1.0f : (_Float16)0.0f;
    bf[4] = bf[5] = bf[6] = bf[7] = (_Float16)0.0f;

    f32x16 zacc;
    f32x16 vmin;
#pragma unroll
    for (int r = 0; r < 16; ++r) { zacc[r] = 0.0f; vmin[r] = INFINITY; }

#define MF(X)                                                              \
    __builtin_amdgcn_mfma_f32_32x32x16_f16(                                \
        __builtin_bit_cast(f16x8, make_uint4((X).x, (X).y, 0u, 0u)),       \
        bf, zacc, 0, 0, 0)

// vmin[r] = min3(vmin[r], A0[r], A1[r]); "v" constraints force VGPRs.
#define FOLD(A0, A1)                                                       \
    {                                                                      \
        _Pragma("unroll")                                                  \
        for (int r = 0; r < 16; ++r) {                                     \
            float t_;                                                      \
            asm("v_min3_f32 %0, %1, %2, %3"                                \
                : "=v"(t_)                                                 \
                : "v"(vmin[r]), "v"((A0)[r]), "v"((A1)[r]));               \
            vmin[r] = t_;                                                  \
        }                                                                  \
    }

    const int nchunks = N / YCHUNK;   // 2
    for (int c = 0; c < nchunks; ++c) {
        __syncthreads();  // previous compute phase done reading sy
        {
            const float4* yf4 = (const float4*)(ysrc + (size_t)b * N * 3
                                                + (size_t)c * YCHUNK * 3);
#pragma unroll
            for (int k = 0; k < 4; ++k) {
                const int fb = k * THREADS * 3 + tid * 3;
                packwrite(&sy[(k * THREADS + tid) * 4], yf4[fb], yf4[fb + 1],
                          yf4[fb + 2]);
            }
        }
        __syncthreads();

        // Depth-2 pair pipeline over 128 row-groups (64 pairs).
        uint2 la0 = sy[0 * 32 + col], la1 = sy[1 * 32 + col];
        f32x16 aa0 = MF(la0), aa1 = MF(la1);
        for (int g = 2; g <= 122; g += 4) {
            uint2 lb0 = sy[(g + 0) * 32 + col];
            uint2 lb1 = sy[(g + 1) * 32 + col];
            f32x16 ab0 = MF(lb0), ab1 = MF(lb1);
            FOLD(aa0, aa1);              // fold pair A (issued last step)
            uint2 lc0 = sy[(g + 2) * 32 + col];
            uint2 lc1 = sy[(g + 3) * 32 + col];
            aa0 = MF(lc0); aa1 = MF(lc1);
            FOLD(ab0, ab1);              // fold pair B
        }
        // Tail: pair (126,127) + the pair A left from the last iteration.
        {
            uint2 lb0 = sy[126 * 32 + col];
            uint2 lb1 = sy[127 * 32 + col];
            f32x16 ab0 = MF(lb0), ab1 = MF(lb1);
            FOLD(aa0, aa1);
            FOLD(ab0, ab1);
        }
    }
#undef MF
#undef FOLD

    // Reduce 16 regs -> 1, then across the two row-halves (lane ^ 32).
    float v = vmin[0];
#pragma unroll
    for (int r = 1; r < 16; ++r) v = fminf(v, vmin[r]);
    v = fminf(v, __shfl_xor(v, 32));
    float d = v + fmaf(x0, x0, fmaf(x1, x1, x2 * x2));  // + |x|^2 in f32

    // Sum d over the 32 cols of this wave (both halves hold identical values).
#pragma unroll
    for (int off = 16; off > 0; off >>= 1) d += __shfl_xor(d, off);
    if (lane == 0) swave[wave] = d;
    __syncthreads();
    if (tid == 0) {
        float s = swave[0] + swave[1] + swave[2] + swave[3];
        int bid = blockIdx.x + gridDim.x * (blockIdx.y + gridDim.y * blockIdx.z);
        partials[bid] = s;
    }
}

// Sum all 512 block partials; dist = sum / (B*N); out = (loss, dist, rate).
__global__ __launch_bounds__(512) void finalize(
    const float* __restrict__ partials, const float* __restrict__ fbpp,
    float* __restrict__ out, int nPartials, int totalPts)
{
    __shared__ float sw[8];
    const int tid = threadIdx.x;
    float v = (tid < nPartials) ? partials[tid] : 0.0f;
#pragma unroll
    for (int off = 32; off > 0; off >>= 1) v += __shfl_xor(v, off);
    if ((tid & 63) == 0) sw[tid >> 6] = v;
    __syncthreads();
    if (tid == 0) {
        float t = 0.0f;
#pragma unroll
        for (int w = 0; w < 8; ++w) t += sw[w];
        float dist = t / (float)totalPts;
        float rate = fbpp[0];
        out[0] = dist + rate;
        out[1] = dist;
        out[2] = rate;
    }
}

extern "C" void kernel_launch(void* const* d_in, const int* in_sizes, int n_in,
                              void* d_out, int out_size, void* d_ws, size_t ws_size,
                              hipStream_t stream) {
    const float* pred = (const float*)d_in[0];
    const float* targ = (const float*)d_in[1];
    const float* fbpp = (const float*)d_in[2];
    float* out = (float*)d_out;

    const int B = 4;
    const int N = in_sizes[0] / (B * 3);   // 8192
    float* partials = (float*)d_ws;        // 512 floats

    dim3 grid(N / XPB, B, 2);              // (64, 4, 2) = 512 blocks
    chamfer_kernel<<<grid, THREADS, 0, stream>>>(pred, targ, partials, N);

    const int nPartials = (N / XPB) * B * 2;  // 512
    finalize<<<1, 512, 0, stream>>>(partials, fbpp, out, nPartials, B * N);
}

// Round 16
// 23.314 us; speedup vs baseline: 5.3374x; 1.0691x over previous
//
#include <hip/hip_runtime.h>
#include <math.h>

typedef _Float16 f16x8 __attribute__((ext_vector_type(8)));
typedef __fp16   fp16v2 __attribute__((ext_vector_type(2)));
typedef float    f32x16 __attribute__((ext_vector_type(16)));

#define THREADS 256
#define YCHUNK  4096  // y points per LDS chunk (32 KB)
#define XPB     128   // x points per block = 2 col-sets * 64

static __device__ inline unsigned pk2(float a, float b) {
    fp16v2 h = __builtin_amdgcn_cvt_pkrtz(a, b);
    return __builtin_bit_cast(unsigned, h);
}

static __device__ inline void packwrite(uint2* dst, float4 f0, float4 f1,
                                        float4 f2) {
    float n0 = fmaf(f0.x, f0.x, fmaf(f0.y, f0.y, f0.z * f0.z));
    float n1 = fmaf(f0.w, f0.w, fmaf(f1.x, f1.x, f1.y * f1.y));
    float n2 = fmaf(f1.z, f1.z, fmaf(f1.w, f1.w, f2.x * f2.x));
    float n3 = fmaf(f2.y, f2.y, fmaf(f2.z, f2.z, f2.w * f2.w));
    dst[0] = make_uint2(pk2(f0.x, f0.y), pk2(f0.z, n0));
    dst[1] = make_uint2(pk2(f0.w, f1.x), pk2(f1.y, n1));
    dst[2] = make_uint2(pk2(f1.z, f1.w), pk2(f2.x, n2));
    dst[3] = make_uint2(pk2(f2.y, f2.z), pk2(f2.w, n3));
}

// R14 structure (each wave: 64 x-cols via TWO B-frags, HALF the y rows ->
// per-CU LDS reads halved; y-half mins merge in-LDS) with the inline-asm
// min3 fold REMOVED: R13/R14 evidence says asm reads of MFMA results skip
// the compiler's MFMA->VALU hazard handling (absmax drifted 0.0039->0.0049
// on a bit-exact-invariant reorder, then blew up at closer distance).
// Plain fminf folds are the R3-R12 proven-correct path.
__global__ __launch_bounds__(THREADS, 2) void chamfer_kernel(
    const float* __restrict__ pred, const float* __restrict__ targ,
    float* __restrict__ partials, int N)
{
    const int dir = blockIdx.z;
    const float* xsrc = dir == 0 ? pred : targ;
    const float* ysrc = dir == 0 ? targ : pred;
    const int b = blockIdx.y;

    __shared__ uint2 sy[YCHUNK];
    __shared__ float sdm[2][XPB];   // [y-half][col] per-col mins (pre-merge)
    __shared__ float swave[2];

    const int tid  = threadIdx.x;
    const int lane = tid & 63;
    const int wave = tid >> 6;     // 0..3
    const int cs   = wave & 1;     // col-set (which 64 x-cols)
    const int h    = wave >> 1;    // y half
    const int col  = lane & 31;

    // Two x columns per lane (lanes 32-63 duplicate lanes 0-31).
    const int    xb  = blockIdx.x * XPB + cs * 64 + col;
    const size_t xiL = (size_t)(b * N + xb) * 3;
    const size_t xiH = (size_t)(b * N + xb + 32) * 3;
    const float xl0 = xsrc[xiL], xl1 = xsrc[xiL + 1], xl2 = xsrc[xiL + 2];
    const float xh0 = xsrc[xiH], xh1 = xsrc[xiH + 1], xh2 = xsrc[xiH + 2];

    const bool act = lane < 32;
    f16x8 bfl, bfh;
    bfl[0] = act ? (_Float16)(-2.0f * xl0) : (_Float16)0.0f;
    bfl[1] = act ? (_Float16)(-2.0f * xl1) : (_Float16)0.0f;
    bfl[2] = act ? (_Float16)(-2.0f * xl2) : (_Float16)0.0f;
    bfl[3] = act ? (_Float16)1.0f : (_Float16)0.0f;
    bfl[4] = bfl[5] = bfl[6] = bfl[7] = (_Float16)0.0f;
    bfh[0] = act ? (_Float16)(-2.0f * xh0) : (_Float16)0.0f;
    bfh[1] = act ? (_Float16)(-2.0f * xh1) : (_Float16)0.0f;
    bfh[2] = act ? (_Float16)(-2.0f * xh2) : (_Float16)0.0f;
    bfh[3] = act ? (_Float16)1.0f : (_Float16)0.0f;
    bfh[4] = bfh[5] = bfh[6] = bfh[7] = (_Float16)0.0f;

    f32x16 zacc;
    f32x16 vmin0, vmin1;
#pragma unroll
    for (int r = 0; r < 16; ++r) {
        zacc[r] = 0.0f; vmin0[r] = INFINITY; vmin1[r] = INFINITY;
    }

#define MF(X, BF)                                                          \
    __builtin_amdgcn_mfma_f32_32x32x16_f16(                                \
        __builtin_bit_cast(f16x8, make_uint4((X).x, (X).y, 0u, 0u)),       \
        BF, zacc, 0, 0, 0)

    const int nchunks = N / YCHUNK;   // 2
    for (int c = 0; c < nchunks; ++c) {
        __syncthreads();  // previous compute phase done reading sy
        {
            const float4* yf4 = (const float4*)(ysrc + (size_t)b * N * 3
                                                + (size_t)c * YCHUNK * 3);
#pragma unroll
            for (int k = 0; k < 4; ++k) {
                const int fb = k * THREADS * 3 + tid * 3;
                packwrite(&sy[(k * THREADS + tid) * 4], yf4[fb], yf4[fb + 1],
                          yf4[fb + 2]);
            }
        }
        __syncthreads();

        // This wave's y-half: 64 row-groups; one A-read feeds TWO MFMAs.
        const int gb = h * 64;
        for (int g = 0; g < 64; g += 2) {
            uint2 a0 = sy[(gb + g) * 32 + col];
            uint2 a1 = sy[(gb + g + 1) * 32 + col];
            f32x16 m0 = MF(a0, bfl);
            f32x16 m1 = MF(a1, bfl);
            f32x16 m2 = MF(a0, bfh);
            f32x16 m3 = MF(a1, bfh);
#pragma unroll
            for (int r = 0; r < 16; ++r) {
                vmin0[r] = fminf(fminf(vmin0[r], m0[r]), m1[r]);  // v_min3
                vmin1[r] = fminf(fminf(vmin1[r], m2[r]), m3[r]);
            }
        }
    }
#undef MF

    // Fold 16 regs -> 1, merge row-halves (lane^32), add |x|^2 in f32.
    float v0 = vmin0[0], v1 = vmin1[0];
#pragma unroll
    for (int r = 1; r < 16; ++r) {
        v0 = fminf(v0, vmin0[r]); v1 = fminf(v1, vmin1[r]);
    }
    v0 = fminf(v0, __shfl_xor(v0, 32));
    v1 = fminf(v1, __shfl_xor(v1, 32));
    const float dlo = v0 + fmaf(xl0, xl0, fmaf(xl1, xl1, xl2 * xl2));
    const float dhi = v1 + fmaf(xh0, xh0, fmaf(xh1, xh1, xh2 * xh2));

    if (act) {
        sdm[h][cs * 64 + col]      = dlo;
        sdm[h][cs * 64 + 32 + col] = dhi;
    }
    __syncthreads();

    // Merge the two y-halves per col, then sum 128 cols (waves 0-1).
    if (tid < 128) {
        float m = fminf(sdm[0][tid], sdm[1][tid]);
#pragma unroll
        for (int off = 32; off > 0; off >>= 1) m += __shfl_xor(m, off);
        if ((tid & 63) == 0) swave[tid >> 6] = m;
    }
    __syncthreads();
    if (tid == 0) {
        int bid = blockIdx.x + gridDim.x * (blockIdx.y + gridDim.y * blockIdx.z);
        partials[bid] = swave[0] + swave[1];
    }
}

// Sum all 512 block partials; dist = sum / (B*N); out = (loss, dist, rate).
__global__ __launch_bounds__(512) void finalize(
    const float* __restrict__ partials, const float* __restrict__ fbpp,
    float* __restrict__ out, int nPartials, int totalPts)
{
    __shared__ float sw[8];
    const int tid = threadIdx.x;
    float v = (tid < nPartials) ? partials[tid] : 0.0f;
#pragma unroll
    for (int off = 32; off > 0; off >>= 1) v += __shfl_xor(v, off);
    if ((tid & 63) == 0) sw[tid >> 6] = v;
    __syncthreads();
    if (tid == 0) {
        float t = 0.0f;
#pragma unroll
        for (int w = 0; w < 8; ++w) t += sw[w];
        float dist = t / (float)totalPts;
        float rate = fbpp[0];
        out[0] = dist + rate;
        out[1] = dist;
        out[2] = rate;
    }
}

extern "C" void kernel_launch(void* const* d_in, const int* in_sizes, int n_in,
                              void* d_out, int out_size, void* d_ws, size_t ws_size,
                              hipStream_t stream) {
    const float* pred = (const float*)d_in[0];
    const float* targ = (const float*)d_in[1];
    const float* fbpp = (const float*)d_in[2];
    float* out = (float*)d_out;

    const int B = 4;
    const int N = in_sizes[0] / (B * 3);   // 8192
    float* partials = (float*)d_ws;        // 512 floats

    dim3 grid(N / XPB, B, 2);              // (64, 4, 2) = 512 blocks
    chamfer_kernel<<<grid, THREADS, 0, stream>>>(pred, targ, partials, N);

    const int nPartials = (N / XPB) * B * 2;  // 512
    finalize<<<1, 512, 0, stream>>>(partials, fbpp, out, nPartials, B * N);
}